// Round 6
// baseline (22190.419 us; speedup 1.0000x reference)
//
#include <hip/hip_runtime.h>
#include <hip/hip_bf16.h>

#define SLEN 2048
#define BROWS 64
#define IDIM 512
#define HDIM 512
#define NWG 64
#define NTHREADS 512

typedef __bf16 bf16x8 __attribute__((ext_vector_type(8)));
typedef float  f32x4  __attribute__((ext_vector_type(4)));
typedef int    i32x4  __attribute__((ext_vector_type(4)));

__device__ inline unsigned short f2bf(float f) {
  union { float f; unsigned u; } v; v.f = f;
  unsigned r = v.u + 0x7FFFu + ((v.u >> 16) & 1u);
  return (unsigned short)(r >> 16);
}
__device__ inline float sigm(float x) {
  return __builtin_amdgcn_rcpf(1.f + __expf(-x));
}
__device__ inline float tanh_f(float x) {
  float e = __expf(2.f * x);
  return 1.f - 2.f * __builtin_amdgcn_rcpf(e + 1.f);
}

// CT[row][k], row-major K=1024. row = w*128 + p*32 + nt*16 + nn
//   j = gate*512 + hcol ; gate = nt*2 + (nn>>3) ; hcol = w*32 + p*8 + (nn&7)
__global__ __launch_bounds__(256) void prep_ct(const float* __restrict__ W,
                                               const float* __restrict__ U,
                                               unsigned short* __restrict__ CT) {
  int k = blockIdx.x;
  const float* src = (k < IDIM) ? (W + (size_t)k * 2048) : (U + (size_t)(k - IDIM) * 2048);
  for (int j = threadIdx.x; j < 2048; j += 256) {
    int gate = j >> 9, hcol = j & 511;
    int w = hcol >> 5, p = (hcol >> 3) & 3, sub = hcol & 7;
    int nt = gate >> 1, nn = ((gate & 1) << 3) | sub;
    int row = w * 128 + p * 32 + nt * 16 + nn;
    CT[(size_t)row * 1024 + k] = f2bf(src[j]);
  }
}

__global__ __launch_bounds__(NTHREADS)
__attribute__((amdgpu_waves_per_eu(2, 2)))
void lstm_persist(const float* __restrict__ x, const float* __restrict__ bias,
                  const unsigned short* __restrict__ CT,
                  unsigned short* __restrict__ hR,   // [8][64][512] bf16, 0xFF-init
                  float* __restrict__ out) {
  const int bid  = blockIdx.x;
  const int g    = bid & 3;            // batch rows [16g, 16g+16)
  const int w    = bid >> 2;           // hcols [32w, 32w+32)
  const int tid  = threadIdx.x;
  const int lane = tid & 63;
  const int wid  = tid >> 6;
  const int lg   = lane >> 4;
  const int lc   = lane & 15;
  const bool isrec = wid < 4;
  const int p = isrec ? wid : wid - 4;

  __shared__ unsigned short Ulds[128 * 512];     // 128 KB, XOR-swizzled
  __shared__ f32x4 ring[2][4][2][64];            // 16 KB: xW+bias handoff
  __shared__ unsigned short stag[4][16][8];      // 1 KB: h transpose staging

  // ---- cooperative U -> LDS (swizzled: chunk16 ^ ((row&7)<<4)) ----
  #pragma unroll
  for (int i = 0; i < 16; ++i) {
    int idx16 = tid + NTHREADS * i;              // 0..8191
    int r = idx16 >> 6, c16 = idx16 & 63;
    i32x4 v = *(const i32x4*)(CT + (size_t)(w * 128 + r) * 1024 + 512 + c16 * 8);
    *(i32x4*)((char*)Ulds + r * 1024 + ((c16 * 16) ^ ((r & 7) << 4))) = v;
  }

  // ---- producer W-weights in registers ----
  i32x4 Wf0[16], Wf1[16];
  if (!isrec) {
    const unsigned short* ctb = CT + (size_t)(w * 128 + p * 32) * 1024;
    #pragma unroll
    for (int kk = 0; kk < 16; ++kk) {
      Wf0[kk] = *(const i32x4*)(ctb + (size_t)lc * 1024 + kk * 32 + lg * 8);
      Wf1[kk] = *(const i32x4*)(ctb + (size_t)(16 + lc) * 1024 + kk * 32 + lg * 8);
    }
    #pragma unroll
    for (int kk = 0; kk < 16; ++kk) {
      asm volatile("" : "+v"(Wf0[kk]));
      asm volatile("" : "+v"(Wf1[kk]));
    }
  }

  float bias_v[2];
  #pragma unroll
  for (int nt = 0; nt < 2; ++nt) {
    int gate = nt * 2 + (lc >> 3);
    int hc = w * 32 + p * 8 + (lc & 7);
    bias_v[nt] = bias[gate * HDIM + hc];
  }

  const float* xbase = x + ((size_t)16 * g + lc) * IDIM + lg * 8;

  auto PROD = [&](int tt, int slot) {
    f32x4 pa0 = {bias_v[0], bias_v[0], bias_v[0], bias_v[0]};
    f32x4 pa1 = {bias_v[1], bias_v[1], bias_v[1], bias_v[1]};
    const float* xp = xbase + (size_t)tt * (BROWS * IDIM);
    #pragma unroll
    for (int kk = 0; kk < 16; ++kk) {
      f32x4 v0 = *(const f32x4*)(xp + kk * 32);
      f32x4 v1 = *(const f32x4*)(xp + kk * 32 + 4);
      bf16x8 a;
      #pragma unroll
      for (int j = 0; j < 4; ++j) { a[j] = (__bf16)v0[j]; a[4 + j] = (__bf16)v1[j]; }
      union { i32x4 i; bf16x8 h; } u0, u1;
      u0.i = Wf0[kk]; u1.i = Wf1[kk];
      pa0 = __builtin_amdgcn_mfma_f32_16x16x32_bf16(a, u0.h, pa0, 0, 0, 0);
      pa1 = __builtin_amdgcn_mfma_f32_16x16x32_bf16(a, u1.h, pa1, 0, 0, 0);
    }
    ring[slot][p][0][lane] = pa0;
    ring[slot][p][1][lane] = pa1;
  };

  if (!isrec) PROD(0, 0);
  __syncthreads();   // Ulds + ring slot 0 ready

  float cst[4] = {0.f, 0.f, 0.f, 0.f};
  const bool lo = (lc < 8);
  const int hcol = w * 32 + p * 8 + (lc & 7);
  const int sw = (lc & 7) << 4;
  const size_t HS = (size_t)SLEN * BROWS * HDIM;
  // per-lane A-chunk base (row = 16g+lc, 16B chunk at kk*64 + lg*16)
  const char* apoll = (const char*)hR + ((size_t)16 * g + lc) * 1024 + lg * 16;

  for (int t = 0; t < SLEN; ++t) {
    if (isrec) {
      f32x4 acc0 = ring[t & 1][p][0][lane];
      f32x4 acc1 = ring[t & 1][p][1][lane];

      if (t > 0) {
        // ---- sentinel-poll read of h(t-1): data IS the flag ----
        const char* ap = apoll + (size_t)((t - 1) & 7) * 65536;
        i32x4 A[16];
        int bad;
        do {
          #pragma unroll
          for (int kk = 0; kk < 16; ++kk)
            asm volatile("global_load_dwordx4 %0, %1, off sc0 sc1"
                         : "=v"(A[kk]) : "v"(ap + kk * 64));
          asm volatile("s_waitcnt vmcnt(0)" ::: "memory");
          bad = 0;
          #pragma unroll
          for (int kk = 0; kk < 16; ++kk)
            #pragma unroll
            for (int j = 0; j < 4; ++j) {
              unsigned d = (unsigned)A[kk][j];
              bad |= ((d & 0xFFFFu) == 0xFFFFu) | ((d >> 16) == 0xFFFFu);
            }
        } while (__ballot(bad) != 0ull);
        __builtin_amdgcn_sched_barrier(0);

        // ---- U-GEMM from swizzled LDS ----
        #pragma unroll
        for (int kk = 0; kk < 16; ++kk) {
          int cb = (kk * 64 + lg * 16) ^ sw;
          bf16x8 b0 = *(const bf16x8*)((const char*)Ulds + (p * 32 + lc) * 1024 + cb);
          bf16x8 b1 = *(const bf16x8*)((const char*)Ulds + (p * 32 + 16 + lc) * 1024 + cb);
          union { i32x4 i; bf16x8 h; } ua;
          ua.i = A[kk];
          acc0 = __builtin_amdgcn_mfma_f32_16x16x32_bf16(ua.h, b0, acc0, 0, 0, 0);
          acc1 = __builtin_amdgcn_mfma_f32_16x16x32_bf16(ua.h, b1, acc1, 0, 0, 0);
        }
      }

      // ---- epilogue ----
      #pragma unroll
      for (int reg = 0; reg < 4; ++reg) {
        float gi = acc0[reg];
        float gf = __shfl_xor(acc0[reg], 8, 64);
        float gg = acc1[reg];
        float go = __shfl_xor(acc1[reg], 8, 64);
        float it = sigm(gi), ft = sigm(gf), gt = tanh_f(gg), ot = sigm(go);
        float cn = ft * cst[reg] + it * gt;
        cst[reg] = cn;
        float hn = ot * tanh_f(cn);
        if (lo) {
          int bl = 4 * lg + reg;
          size_t bglob = (size_t)16 * g + bl;
          out[(size_t)t * (BROWS * HDIM) + bglob * HDIM + hcol] = hn;
          stag[p][bl][lc & 7] = f2bf(hn);
          if (t == SLEN - 1) {
            out[HS + bglob * HDIM + hcol] = hn;
            out[HS + BROWS * HDIM + bglob * HDIM + hcol] = cn;
          }
        }
      }

      // ---- coalesced h-store (16B/lane) + future-buffer sentinel reset ----
      if (t + 1 < SLEN && lane < 16) {
        i32x4 hv = *(const i32x4*)&stag[p][lane][0];   // compiler inserts lgkmcnt
        char* d0 = (char*)hR + (size_t)(t & 7) * 65536
                 + ((size_t)16 * g + lane) * 1024 + w * 64 + p * 16;
        asm volatile("global_store_dwordx4 %0, %1, off sc0 sc1"
                     :: "v"(d0), "v"(hv) : "memory");
        i32x4 ff = {-1, -1, -1, -1};
        char* d1 = (char*)hR + (size_t)((t + 3) & 7) * 65536
                 + ((size_t)16 * g + lane) * 1024 + w * 64 + p * 16;
        asm volatile("global_store_dwordx4 %0, %1, off sc0 sc1"
                     :: "v"(d1), "v"(ff) : "memory");
      }
    } else if (t + 1 < SLEN) {
      PROD(t + 1, (t + 1) & 1);
    }

    __syncthreads();   // intra-WG: ring slot handoff
  }
}

extern "C" void kernel_launch(void* const* d_in, const int* in_sizes, int n_in,
                              void* d_out, int out_size, void* d_ws, size_t ws_size,
                              hipStream_t stream) {
  const float* x    = (const float*)d_in[0];
  const float* W    = (const float*)d_in[1];
  const float* U    = (const float*)d_in[2];
  const float* bias = (const float*)d_in[3];
  float* out = (float*)d_out;

  unsigned short* CT = (unsigned short*)d_ws;                                    // 4 MiB
  unsigned short* hR = (unsigned short*)((char*)d_ws + (size_t)2048 * 1024 * 2); // 512 KiB

  hipMemsetAsync(hR, 0xFF, (size_t)8 * BROWS * HDIM * 2, stream);
  prep_ct<<<1024, 256, 0, stream>>>(W, U, CT);
  lstm_persist<<<NWG, NTHREADS, 0, stream>>>(x, bias, CT, hR, out);
}